// Round 6
// baseline (144.882 us; speedup 1.0000x reference)
//
#include <hip/hip_runtime.h>

#define SEQ  1024
#define HD   64
#define QTB  128
#define NT   16
#define RING 192
#define PST  84
#define WSTR (16*PST)    // per-wave strip stride (16 query cols)
#define FB   (8*WSTR)    // fallback column base
#define L2E  1.44269504f

typedef __attribute__((ext_vector_type(8))) _Float16 f16x8;
typedef __attribute__((ext_vector_type(4))) _Float16 f16x4;
typedef __attribute__((ext_vector_type(2))) _Float16 f16x2;
typedef __attribute__((ext_vector_type(4))) float    f32x4;

#define MFMA16(a,b,c) __builtin_amdgcn_mfma_f32_16x16x32_f16(a,b,c,0,0,0)

// swizzled element index into a [rows][64] f16 tile (128B rows)
__device__ __forceinline__ int sw(int row, int c) {
    return (row << 6) + (c ^ ((row & 7) << 3));
}
__device__ __forceinline__ float4 ld4(const float* p) { return *(const float4*)p; }
__device__ __forceinline__ f16x8 cvt8(float4 a, float4 b) {
    return (f16x8){(_Float16)a.x,(_Float16)a.y,(_Float16)a.z,(_Float16)a.w,
                   (_Float16)b.x,(_Float16)b.y,(_Float16)b.z,(_Float16)b.w};
}
// (q*K^-0.5 + bias) * log2(e)  -> scores arrive in log2 domain
__device__ __forceinline__ f16x8 biasf8(float4 qa, float4 qb, float4 ba, float4 bb) {
    return (f16x8){(_Float16)(fmaf(qa.x,0.125f,ba.x)*L2E),(_Float16)(fmaf(qa.y,0.125f,ba.y)*L2E),
                   (_Float16)(fmaf(qa.z,0.125f,ba.z)*L2E),(_Float16)(fmaf(qa.w,0.125f,ba.w)*L2E),
                   (_Float16)(fmaf(qb.x,0.125f,bb.x)*L2E),(_Float16)(fmaf(qb.y,0.125f,bb.y)*L2E),
                   (_Float16)(fmaf(qb.z,0.125f,bb.z)*L2E),(_Float16)(fmaf(qb.w,0.125f,bb.w)*L2E)};
}
__device__ __forceinline__ unsigned pk2(float x, float y) {
    f16x2 h = {(_Float16)x, (_Float16)y};
    return __builtin_bit_cast(unsigned, h);
}
__device__ __forceinline__ f16x8 mk8(unsigned a, unsigned b, unsigned c, unsigned d) {
    union { unsigned u[4]; f16x8 v; } x;
    x.u[0]=a; x.u[1]=b; x.u[2]=c; x.u[3]=d; return x.v;
}

__global__ __launch_bounds__(512)
__attribute__((amdgpu_waves_per_eu(4, 4)))
void rpsdpa6(const float* __restrict__ Q, const float* __restrict__ Km,
             const float* __restrict__ Vm, const float* __restrict__ UB,
             const float* __restrict__ VB, const float* __restrict__ Rm,
             float* __restrict__ O)
{
    __shared__ __attribute__((aligned(16))) _Float16 sK[64*64];
    __shared__ __attribute__((aligned(16))) _Float16 sVt[2][64*64];
    __shared__ __attribute__((aligned(16))) _Float16 sR[RING*64];
    __shared__ __attribute__((aligned(16))) _Float16 sPT[FB + PST];
    __shared__ __attribute__((aligned(16))) _Float16 sQx[64];

    const int tid  = threadIdx.x;
    const int wv   = tid >> 6;
    const int lane = tid & 63;
    const int q    = lane & 15;
    const int G    = lane >> 4;

    // head-major XCD swizzle: XCD (= bid%8) carries heads {x, x+8} only,
    // so the per-head R table is L2-resident per XCD.
    const int bid = blockIdx.x;
    const int x   = bid & 7;
    const int y   = bid >> 3;
    const int h   = x + ((y & 1) << 3);
    const int n   = (y >> 1) & 3;
    const int bh  = n * 16 + h;
    const int i0  = (y >> 3) * QTB;

    const float* Qb = Q  + (size_t)bh * SEQ * HD;
    const float* Kb = Km + (size_t)bh * SEQ * HD;
    const float* Vb = Vm + (size_t)bh * SEQ * HD;
    const float* Rh = Rm + (size_t)h * 2048 * HD;

    // ---- qu/qv B-fragments: this lane's query row = i0 + 16*wv + q ----
    f16x8 qu0, qu1, qvf0, qvf1;
    {
        const float* qr = Qb + (size_t)(i0 + 16*wv + q) * HD;
        const float* ub = UB + h * HD;
        const float* vb = VB + h * HD;
        {   int c = 8*G;
            float4 qa = ld4(qr+c), qb2 = ld4(qr+c+4);
            qu0  = biasf8(qa,qb2, ld4(ub+c), ld4(ub+c+4));
            qvf0 = biasf8(qa,qb2, ld4(vb+c), ld4(vb+c+4)); }
        {   int c = 32 + 8*G;
            float4 qa = ld4(qr+c), qb2 = ld4(qr+c+4);
            qu1  = biasf8(qa,qb2, ld4(ub+c), ld4(ub+c+4));
            qvf1 = biasf8(qa,qb2, ld4(vb+c), ld4(vb+c+4)); }
    }
    // ---- sQx: q_v row i0+128 (fallback column source), log2-scaled ----
    if (tid < 16) {
        int c0 = tid * 4;
        float4 v = make_float4(0.f,0.f,0.f,0.f);
        if (i0 + 128 < SEQ) {
            float4 q4 = ld4(Qb + (size_t)(i0+128)*HD + c0);
            float4 b4 = ld4(VB + h*HD + c0);
            v = make_float4(fmaf(q4.x,0.125f,b4.x)*L2E, fmaf(q4.y,0.125f,b4.y)*L2E,
                            fmaf(q4.z,0.125f,b4.z)*L2E, fmaf(q4.w,0.125f,b4.w)*L2E);
        }
        *(f16x4*)&sQx[c0] = (f16x4){(_Float16)v.x,(_Float16)v.y,(_Float16)v.z,(_Float16)v.w};
    }
    // ---- prologue staging ----
    const int rK  = tid >> 3;            // 0..63
    const int cK  = (tid & 7) * 8;       // 0..56
    const int kp2 = (tid & 31) * 2;      // 0..62 (V key pair)
    const int d0v = (tid >> 5) * 4;      // 0..60 (V dim chunk)
    {
        const float* s = Kb + (size_t)rK*HD + cK;
        *(f16x8*)&sK[sw(rK, cK)] = cvt8(ld4(s), ld4(s+4));
    }
    {
        const float* sA = Vb + (size_t)kp2*HD + d0v;
        float4 a = ld4(sA), b2 = ld4(sA + HD);
        _Float16* vt = sVt[0];
        *(f16x2*)&vt[sw(d0v+0, kp2)] = (f16x2){(_Float16)a.x,(_Float16)b2.x};
        *(f16x2*)&vt[sw(d0v+1, kp2)] = (f16x2){(_Float16)a.y,(_Float16)b2.y};
        *(f16x2*)&vt[sw(d0v+2, kp2)] = (f16x2){(_Float16)a.z,(_Float16)b2.z};
        *(f16x2*)&vt[sw(d0v+3, kp2)] = (f16x2){(_Float16)a.w,(_Float16)b2.w};
    }
#pragma unroll 1
    for (int p = 0; p < 3; ++p) {
        int d = -i0 - 127 + p*64 + rK;
        int row = (d <= 0) ? (1023 + d) : ((d >= 2) ? d - 2 : 0);
        int slot = (d + 1536) % RING;
        const float* s = Rh + (size_t)row*HD + cK;
        *(f16x8*)&sR[sw(slot, cK)] = cvt8(ld4(s), ld4(s+4));
    }
    __syncthreads();

    int sbase = ((-i0 - 16*wv - 15) + 1536) % RING;
    float m_run = -3.0e38f, l_run = 0.f, corr = 0.f;
    f32x4 o0 = {}, o1 = {}, o2 = {}, o3 = {};
    f16x8 wf0 = {}, wf1 = {};

#pragma unroll 1
    for (int t = 0; t < NT; ++t) {
        const int j0 = t * 64;
        // ---- prefetch tile t+1 ----
        float4 fk0, fk1, fv0, fv1, fr0, fr1;
        if (t + 1 < NT) {
            const float* s = Kb + (size_t)(j0 + 64 + rK)*HD + cK;
            fk0 = ld4(s); fk1 = ld4(s+4);
            const float* sA = Vb + (size_t)(j0 + 64 + kp2)*HD + d0v;
            fv0 = ld4(sA); fv1 = ld4(sA + HD);
            int d = j0 - i0 + 65 + rK;
            int row = (d <= 0) ? (1023 + d) : ((d >= 2) ? d - 2 : 0);
            const float* sr = Rh + (size_t)row*HD + cK;
            fr0 = ld4(sr); fr1 = ld4(sr+4);
        }
        __builtin_amdgcn_s_setprio(1);
        // ---- content: C[key][query], A = K rows, B = qu ----
        f32x4 c0 = {}, c1 = {}, c2 = {}, c3 = {};
        {
            int cc = 8*G;
            c0 = MFMA16(*(const f16x8*)&sK[sw( 0+q, cc)], qu0, c0);
            c1 = MFMA16(*(const f16x8*)&sK[sw(16+q, cc)], qu0, c1);
            c2 = MFMA16(*(const f16x8*)&sK[sw(32+q, cc)], qu0, c2);
            c3 = MFMA16(*(const f16x8*)&sK[sw(48+q, cc)], qu0, c3);
            cc = 32 + 8*G;
            c0 = MFMA16(*(const f16x8*)&sK[sw( 0+q, cc)], qu1, c0);
            c1 = MFMA16(*(const f16x8*)&sK[sw(16+q, cc)], qu1, c1);
            c2 = MFMA16(*(const f16x8*)&sK[sw(32+q, cc)], qu1, c2);
            c3 = MFMA16(*(const f16x8*)&sK[sw(48+q, cc)], qu1, c3);
        }
        // ---- pos band: C[bandpos][query], A = R band rows, B = qv ----
        f32x4 p0 = {}, p1 = {}, p2 = {}, p3 = {}, p4 = {};
        {
            int r0 = sbase + q;       if (r0 >= RING) r0 -= RING;
            int r1 = sbase + 16 + q;  if (r1 >= RING) r1 -= RING;
            int r2 = sbase + 32 + q;  if (r2 >= RING) r2 -= RING;
            int r3 = sbase + 48 + q;  if (r3 >= RING) r3 -= RING;
            int r4 = sbase + 64 + q;  if (r4 >= RING) r4 -= RING;
            int cc = 8*G;
            p0 = MFMA16(*(const f16x8*)&sR[sw(r0, cc)], qvf0, p0);
            p1 = MFMA16(*(const f16x8*)&sR[sw(r1, cc)], qvf0, p1);
            p2 = MFMA16(*(const f16x8*)&sR[sw(r2, cc)], qvf0, p2);
            p3 = MFMA16(*(const f16x8*)&sR[sw(r3, cc)], qvf0, p3);
            p4 = MFMA16(*(const f16x8*)&sR[sw(r4, cc)], qvf0, p4);
            cc = 32 + 8*G;
            p0 = MFMA16(*(const f16x8*)&sR[sw(r0, cc)], qvf1, p0);
            p1 = MFMA16(*(const f16x8*)&sR[sw(r1, cc)], qvf1, p1);
            p2 = MFMA16(*(const f16x8*)&sR[sw(r2, cc)], qvf1, p2);
            p3 = MFMA16(*(const f16x8*)&sR[sw(r3, cc)], qvf1, p3);
            p4 = MFMA16(*(const f16x8*)&sR[sw(r4, cc)], qvf1, p4);
        }
        // ---- scatter band (transposed): sPT[wv][query q][bandrow] ----
        {
            _Float16* dst = &sPT[wv*WSTR + q*PST + 4*G];
            *(f16x4*)&dst[ 0] = (f16x4){(_Float16)p0[0],(_Float16)p0[1],(_Float16)p0[2],(_Float16)p0[3]};
            *(f16x4*)&dst[16] = (f16x4){(_Float16)p1[0],(_Float16)p1[1],(_Float16)p1[2],(_Float16)p1[3]};
            *(f16x4*)&dst[32] = (f16x4){(_Float16)p2[0],(_Float16)p2[1],(_Float16)p2[2],(_Float16)p2[3]};
            *(f16x4*)&dst[48] = (f16x4){(_Float16)p3[0],(_Float16)p3[1],(_Float16)p3[2],(_Float16)p3[3]};
            *(f16x4*)&dst[64] = (f16x4){(_Float16)p4[0],(_Float16)p4[1],(_Float16)p4[2],(_Float16)p4[3]};
        }
        // ---- fallback column (query i0+128), wave 7 only: VALU dots ----
        if (wv == 7) {
            int sl = sbase + lane; if (sl >= RING) sl -= RING;
            float acc = 0.f;
#pragma unroll
            for (int c8 = 0; c8 < 8; ++c8) {
                f16x8 rv = *(const f16x8*)&sR[sw(sl, 8*c8)];
                f16x8 qx = *(const f16x8*)&sQx[8*c8];
#pragma unroll
                for (int e = 0; e < 8; ++e) acc = fmaf((float)rv[e], (float)qx[e], acc);
            }
            sPT[FB + 16 + lane] = (_Float16)acc;
        }
        // ---- PV of tile t-1 ----
        if (t > 0) {
            float cg0 = __shfl(corr, 4*G + 0);
            float cg1 = __shfl(corr, 4*G + 1);
            float cg2 = __shfl(corr, 4*G + 2);
            float cg3 = __shfl(corr, 4*G + 3);
            f32x4 cg = {cg0, cg1, cg2, cg3};
            o0 *= cg; o1 *= cg; o2 *= cg; o3 *= cg;
            const _Float16* vt = sVt[(t-1) & 1];
            int cc = 8*G;
            o0 = MFMA16(wf0, *(const f16x8*)&vt[sw( 0+q, cc)], o0);
            o1 = MFMA16(wf0, *(const f16x8*)&vt[sw(16+q, cc)], o1);
            o2 = MFMA16(wf0, *(const f16x8*)&vt[sw(32+q, cc)], o2);
            o3 = MFMA16(wf0, *(const f16x8*)&vt[sw(48+q, cc)], o3);
            cc = 32 + 8*G;
            o0 = MFMA16(wf1, *(const f16x8*)&vt[sw( 0+q, cc)], o0);
            o1 = MFMA16(wf1, *(const f16x8*)&vt[sw(16+q, cc)], o1);
            o2 = MFMA16(wf1, *(const f16x8*)&vt[sw(32+q, cc)], o2);
            o3 = MFMA16(wf1, *(const f16x8*)&vt[sw(48+q, cc)], o3);
        }
        __builtin_amdgcn_s_setprio(0);
        __syncthreads();
        // ================= gather + softmax + wfrag + stage =================
        {
            const int ii = i0 + 16*wv + q - j0;            // i - j0
            const int b1 = wv*WSTR + q*PST + 15 + 4*G - q; // case1 base (col q)
            const int b2 = b1 + PST + ((q == 15) ? 16 : 0);// case2 base (col q+1 / next strip / fallback)
            float sc[16];
#pragma unroll
            for (int t4 = 0; t4 < 4; ++t4) {
#pragma unroll
                for (int r = 0; r < 4; ++r) {
                    const int off = r + 16*t4;
                    const int jrel = 4*G + off;
                    const float v1 = (float)sPT[b1 + off];
                    const float v2 = (float)sPT[b2 + off];
                    const int dj = jrel - ii;
                    const float add = (dj <= 0) ? v1 : ((dj == 1) ? 0.f : v2);
                    const float cv = (t4 == 0) ? c0[r] : (t4 == 1) ? c1[r] : (t4 == 2) ? c2[r] : c3[r];
                    sc[4*t4 + r] = cv + add;
                }
            }
            float mA = fmaxf(fmaxf(fmaxf(sc[0],sc[1]),fmaxf(sc[2],sc[3])),
                             fmaxf(fmaxf(sc[4],sc[5]),fmaxf(sc[6],sc[7])));
            float mB = fmaxf(fmaxf(fmaxf(sc[8],sc[9]),fmaxf(sc[10],sc[11])),
                             fmaxf(fmaxf(sc[12],sc[13]),fmaxf(sc[14],sc[15])));
            float mx = fmaxf(mA, mB);
            mx = fmaxf(mx, __shfl_xor(mx, 16));
            mx = fmaxf(mx, __shfl_xor(mx, 32));
            const float mnew = fmaxf(m_run, mx);
            corr = exp2f(m_run - mnew);
            m_run = mnew;
#pragma unroll
            for (int i = 0; i < 16; ++i) sc[i] = exp2f(sc[i] - mnew);
            float sA2 = ((sc[0]+sc[1])+(sc[2]+sc[3])) + ((sc[4]+sc[5])+(sc[6]+sc[7]));
            float sB2 = ((sc[8]+sc[9])+(sc[10]+sc[11])) + ((sc[12]+sc[13])+(sc[14]+sc[15]));
            float ssum = sA2 + sB2;
            ssum += __shfl_xor(ssum, 16);
            ssum += __shfl_xor(ssum, 32);
            l_run = l_run * corr + ssum;
            // pack exp'd weights: pkd[2*t4+w]
            unsigned pkd[8];
#pragma unroll
            for (int t4 = 0; t4 < 4; ++t4) {
                pkd[2*t4+0] = pk2(sc[4*t4+0], sc[4*t4+1]);
                pkd[2*t4+1] = pk2(sc[4*t4+2], sc[4*t4+3]);
            }
            const int s0 = q + 32*(G & 1);
            const int s1 = s0 + 16;
            const bool lo = (G < 2);
            {   // kl = 0 : keys 0..31
                unsigned A0 = (unsigned)__shfl((int)pkd[0], s0);
                unsigned A1 = (unsigned)__shfl((int)pkd[1], s0);
                unsigned A2 = (unsigned)__shfl((int)pkd[0], s1);
                unsigned A3 = (unsigned)__shfl((int)pkd[1], s1);
                unsigned B0 = (unsigned)__shfl((int)pkd[2], s0);
                unsigned B1 = (unsigned)__shfl((int)pkd[3], s0);
                unsigned B2 = (unsigned)__shfl((int)pkd[2], s1);
                unsigned B3 = (unsigned)__shfl((int)pkd[3], s1);
                wf0 = mk8(lo?A0:B0, lo?A1:B1, lo?A2:B2, lo?A3:B3);
            }
            {   // kl = 1 : keys 32..63
                unsigned A0 = (unsigned)__shfl((int)pkd[4], s0);
                unsigned A1 = (unsigned)__shfl((int)pkd[5], s0);
                unsigned A2 = (unsigned)__shfl((int)pkd[4], s1);
                unsigned A3 = (unsigned)__shfl((int)pkd[5], s1);
                unsigned B0 = (unsigned)__shfl((int)pkd[6], s0);
                unsigned B1 = (unsigned)__shfl((int)pkd[7], s0);
                unsigned B2 = (unsigned)__shfl((int)pkd[6], s1);
                unsigned B3 = (unsigned)__shfl((int)pkd[7], s1);
                wf1 = mk8(lo?A0:B0, lo?A1:B1, lo?A2:B2, lo?A3:B3);
            }
            // stage tile t+1 from prefetch regs
            if (t + 1 < NT) {
                *(f16x8*)&sK[sw(rK, cK)] = cvt8(fk0, fk1);
                _Float16* vt = sVt[(t+1) & 1];
                *(f16x2*)&vt[sw(d0v+0, kp2)] = (f16x2){(_Float16)fv0.x,(_Float16)fv1.x};
                *(f16x2*)&vt[sw(d0v+1, kp2)] = (f16x2){(_Float16)fv0.y,(_Float16)fv1.y};
                *(f16x2*)&vt[sw(d0v+2, kp2)] = (f16x2){(_Float16)fv0.z,(_Float16)fv1.z};
                *(f16x2*)&vt[sw(d0v+3, kp2)] = (f16x2){(_Float16)fv0.w,(_Float16)fv1.w};
                int d = j0 - i0 + 65 + rK;
                int slot = (d + 1536) % RING;
                *(f16x8*)&sR[sw(slot, cK)] = cvt8(fr0, fr1);
            }
            sbase += 64; if (sbase >= RING) sbase -= RING;
        }
        __syncthreads();
    }
    // ================= epilogue: PV of tile 15 + output =================
    {
        float cg0 = __shfl(corr, 4*G + 0);
        float cg1 = __shfl(corr, 4*G + 1);
        float cg2 = __shfl(corr, 4*G + 2);
        float cg3 = __shfl(corr, 4*G + 3);
        f32x4 cg = {cg0, cg1, cg2, cg3};
        o0 *= cg; o1 *= cg; o2 *= cg; o3 *= cg;
        const _Float16* vt = sVt[(NT-1) & 1];
        int cc = 8*G;
        o0 = MFMA16(wf0, *(const f16x8*)&vt[sw( 0+q, cc)], o0);
        o1 = MFMA16(wf0, *(const f16x8*)&vt[sw(16+q, cc)], o1);
        o2 = MFMA16(wf0, *(const f16x8*)&vt[sw(32+q, cc)], o2);
        o3 = MFMA16(wf0, *(const f16x8*)&vt[sw(48+q, cc)], o3);
        cc = 32 + 8*G;
        o0 = MFMA16(wf1, *(const f16x8*)&vt[sw( 0+q, cc)], o0);
        o1 = MFMA16(wf1, *(const f16x8*)&vt[sw(16+q, cc)], o1);
        o2 = MFMA16(wf1, *(const f16x8*)&vt[sw(32+q, cc)], o2);
        o3 = MFMA16(wf1, *(const f16x8*)&vt[sw(48+q, cc)], o3);
    }
    {
        float i0v = 1.f / __shfl(l_run, 4*G + 0);
        float i1v = 1.f / __shfl(l_run, 4*G + 1);
        float i2v = 1.f / __shfl(l_run, 4*G + 2);
        float i3v = 1.f / __shfl(l_run, 4*G + 3);
        f32x4 inv = {i0v, i1v, i2v, i3v};
#pragma unroll
        for (int reg = 0; reg < 4; ++reg) {
            size_t base = ((size_t)bh*SEQ + i0 + 16*wv + 4*G + reg) * HD + q;
            O[base +  0] = o0[reg] * inv[reg];
            O[base + 16] = o1[reg] * inv[reg];
            O[base + 32] = o2[reg] * inv[reg];
            O[base + 48] = o3[reg] * inv[reg];
        }
    }
}

extern "C" void kernel_launch(void* const* d_in, const int* in_sizes, int n_in,
                              void* d_out, int out_size, void* d_ws, size_t ws_size,
                              hipStream_t stream) {
    const float* Q  = (const float*)d_in[0];
    const float* K  = (const float*)d_in[1];
    const float* V  = (const float*)d_in[2];
    const float* UB = (const float*)d_in[3];
    const float* VB = (const float*)d_in[4];
    const float* R  = (const float*)d_in[5];
    float* O = (float*)d_out;

    rpsdpa6<<<dim3(512), dim3(512), 0, stream>>>(Q, K, V, UB, VB, R, O);
}

// Round 7
// 85.070 us; speedup vs baseline: 1.7031x; 1.7031x over previous
//
#include <hip/hip_runtime.h>

#define SEQ  1024
#define HD   64
#define QTB  128
#define NT   16
#define RING 192
#define PST  84
#define WSTR (16*PST)    // per-wave strip stride (16 query cols)
#define FB   (8*WSTR)    // fallback column base
#define L2E  1.44269504f

typedef __attribute__((ext_vector_type(8))) _Float16 f16x8;
typedef __attribute__((ext_vector_type(4))) _Float16 f16x4;
typedef __attribute__((ext_vector_type(2))) _Float16 f16x2;
typedef __attribute__((ext_vector_type(4))) float    f32x4;

#define MFMA16(a,b,c) __builtin_amdgcn_mfma_f32_16x16x32_f16(a,b,c,0,0,0)

// swizzled element index into a [rows][64] f16 tile (128B rows)
__device__ __forceinline__ int sw(int row, int c) {
    return (row << 6) + (c ^ ((row & 7) << 3));
}
__device__ __forceinline__ float4 ld4(const float* p) { return *(const float4*)p; }
__device__ __forceinline__ f16x8 cvt8(float4 a, float4 b) {
    return (f16x8){(_Float16)a.x,(_Float16)a.y,(_Float16)a.z,(_Float16)a.w,
                   (_Float16)b.x,(_Float16)b.y,(_Float16)b.z,(_Float16)b.w};
}
// (q*K^-0.5 + bias) * log2(e)  -> scores arrive in log2 domain
__device__ __forceinline__ f16x8 biasf8(float4 qa, float4 qb, float4 ba, float4 bb) {
    return (f16x8){(_Float16)(fmaf(qa.x,0.125f,ba.x)*L2E),(_Float16)(fmaf(qa.y,0.125f,ba.y)*L2E),
                   (_Float16)(fmaf(qa.z,0.125f,ba.z)*L2E),(_Float16)(fmaf(qa.w,0.125f,ba.w)*L2E),
                   (_Float16)(fmaf(qb.x,0.125f,bb.x)*L2E),(_Float16)(fmaf(qb.y,0.125f,bb.y)*L2E),
                   (_Float16)(fmaf(qb.z,0.125f,bb.z)*L2E),(_Float16)(fmaf(qb.w,0.125f,bb.w)*L2E)};
}
__device__ __forceinline__ unsigned pk2(float x, float y) {
    f16x2 h = {(_Float16)x, (_Float16)y};
    return __builtin_bit_cast(unsigned, h);
}
__device__ __forceinline__ f16x8 mk8(unsigned a, unsigned b, unsigned c, unsigned d) {
    union { unsigned u[4]; f16x8 v; } x;
    x.u[0]=a; x.u[1]=b; x.u[2]=c; x.u[3]=d; return x.v;
}

__global__ __launch_bounds__(512, 4)
void rpsdpa7(const float* __restrict__ Q, const float* __restrict__ Km,
             const float* __restrict__ Vm, const float* __restrict__ UB,
             const float* __restrict__ VB, const float* __restrict__ Rm,
             float* __restrict__ O)
{
    __shared__ __attribute__((aligned(16))) _Float16 sK[64*64];
    __shared__ __attribute__((aligned(16))) _Float16 sVt[2][64*64];
    __shared__ __attribute__((aligned(16))) _Float16 sR[RING*64];
    __shared__ __attribute__((aligned(16))) _Float16 sPT[FB + PST];
    __shared__ __attribute__((aligned(16))) _Float16 sQx[64];

    const int tid  = threadIdx.x;
    const int wv   = tid >> 6;
    const int lane = tid & 63;
    const int q    = lane & 15;
    const int G    = lane >> 4;

    // head-major XCD swizzle: XCD (= bid%8) carries heads {x, x+8} only,
    // so the per-head R table is L2-resident per XCD.
    const int bid = blockIdx.x;
    const int x   = bid & 7;
    const int y   = bid >> 3;
    const int h   = x + ((y & 1) << 3);
    const int n   = (y >> 1) & 3;
    const int bh  = n * 16 + h;
    const int i0  = (y >> 3) * QTB;

    const float* Qb = Q  + (size_t)bh * SEQ * HD;
    const float* Kb = Km + (size_t)bh * SEQ * HD;
    const float* Vb = Vm + (size_t)bh * SEQ * HD;
    const float* Rh = Rm + (size_t)h * 2048 * HD;

    // ---- qu/qv B-fragments: this lane's query row = i0 + 16*wv + q ----
    f16x8 qu0, qu1, qvf0, qvf1;
    {
        const float* qr = Qb + (size_t)(i0 + 16*wv + q) * HD;
        const float* ub = UB + h * HD;
        const float* vb = VB + h * HD;
        {   int c = 8*G;
            float4 qa = ld4(qr+c), qb2 = ld4(qr+c+4);
            qu0  = biasf8(qa,qb2, ld4(ub+c), ld4(ub+c+4));
            qvf0 = biasf8(qa,qb2, ld4(vb+c), ld4(vb+c+4)); }
        {   int c = 32 + 8*G;
            float4 qa = ld4(qr+c), qb2 = ld4(qr+c+4);
            qu1  = biasf8(qa,qb2, ld4(ub+c), ld4(ub+c+4));
            qvf1 = biasf8(qa,qb2, ld4(vb+c), ld4(vb+c+4)); }
    }
    // ---- sQx: q_v row i0+128 (fallback column source), log2-scaled ----
    if (tid < 16) {
        int c0 = tid * 4;
        float4 v = make_float4(0.f,0.f,0.f,0.f);
        if (i0 + 128 < SEQ) {
            float4 q4 = ld4(Qb + (size_t)(i0+128)*HD + c0);
            float4 b4 = ld4(VB + h*HD + c0);
            v = make_float4(fmaf(q4.x,0.125f,b4.x)*L2E, fmaf(q4.y,0.125f,b4.y)*L2E,
                            fmaf(q4.z,0.125f,b4.z)*L2E, fmaf(q4.w,0.125f,b4.w)*L2E);
        }
        *(f16x4*)&sQx[c0] = (f16x4){(_Float16)v.x,(_Float16)v.y,(_Float16)v.z,(_Float16)v.w};
    }
    // ---- prologue staging ----
    const int rK  = tid >> 3;            // 0..63
    const int cK  = (tid & 7) * 8;       // 0..56
    const int kp2 = (tid & 31) * 2;      // 0..62 (V key pair)
    const int d0v = (tid >> 5) * 4;      // 0..60 (V dim chunk)
    {
        const float* s = Kb + (size_t)rK*HD + cK;
        *(f16x8*)&sK[sw(rK, cK)] = cvt8(ld4(s), ld4(s+4));
    }
    {
        const float* sA = Vb + (size_t)kp2*HD + d0v;
        float4 a = ld4(sA), b2 = ld4(sA + HD);
        _Float16* vt = sVt[0];
        *(f16x2*)&vt[sw(d0v+0, kp2)] = (f16x2){(_Float16)a.x,(_Float16)b2.x};
        *(f16x2*)&vt[sw(d0v+1, kp2)] = (f16x2){(_Float16)a.y,(_Float16)b2.y};
        *(f16x2*)&vt[sw(d0v+2, kp2)] = (f16x2){(_Float16)a.z,(_Float16)b2.z};
        *(f16x2*)&vt[sw(d0v+3, kp2)] = (f16x2){(_Float16)a.w,(_Float16)b2.w};
    }
#pragma unroll 1
    for (int p = 0; p < 3; ++p) {
        int d = -i0 - 127 + p*64 + rK;
        int row = (d <= 0) ? (1023 + d) : ((d >= 2) ? d - 2 : 0);
        int slot = (d + 1536) % RING;
        const float* s = Rh + (size_t)row*HD + cK;
        *(f16x8*)&sR[sw(slot, cK)] = cvt8(ld4(s), ld4(s+4));
    }
    __syncthreads();

    int sbase = ((-i0 - 16*wv - 15) + 1536) % RING;
    float m_run = -3.0e38f, l_run = 0.f, corr = 0.f;
    f32x4 o0 = {}, o1 = {}, o2 = {}, o3 = {};
    f16x8 wf0 = {}, wf1 = {};

#pragma unroll 1
    for (int t = 0; t < NT; ++t) {
        const int j0 = t * 64;
        __builtin_amdgcn_s_setprio(1);
        // ---- content: C[key][query], A = K rows, B = qu ----
        f32x4 c0 = {}, c1 = {}, c2 = {}, c3 = {};
        {
            int cc = 8*G;
            c0 = MFMA16(*(const f16x8*)&sK[sw( 0+q, cc)], qu0, c0);
            c1 = MFMA16(*(const f16x8*)&sK[sw(16+q, cc)], qu0, c1);
            c2 = MFMA16(*(const f16x8*)&sK[sw(32+q, cc)], qu0, c2);
            c3 = MFMA16(*(const f16x8*)&sK[sw(48+q, cc)], qu0, c3);
            cc = 32 + 8*G;
            c0 = MFMA16(*(const f16x8*)&sK[sw( 0+q, cc)], qu1, c0);
            c1 = MFMA16(*(const f16x8*)&sK[sw(16+q, cc)], qu1, c1);
            c2 = MFMA16(*(const f16x8*)&sK[sw(32+q, cc)], qu1, c2);
            c3 = MFMA16(*(const f16x8*)&sK[sw(48+q, cc)], qu1, c3);
        }
        // ---- pos band: C[bandpos][query], A = R band rows, B = qv ----
        f32x4 p0 = {}, p1 = {}, p2 = {}, p3 = {}, p4 = {};
        {
            int r0 = sbase + q;       if (r0 >= RING) r0 -= RING;
            int r1 = sbase + 16 + q;  if (r1 >= RING) r1 -= RING;
            int r2 = sbase + 32 + q;  if (r2 >= RING) r2 -= RING;
            int r3 = sbase + 48 + q;  if (r3 >= RING) r3 -= RING;
            int r4 = sbase + 64 + q;  if (r4 >= RING) r4 -= RING;
            int cc = 8*G;
            p0 = MFMA16(*(const f16x8*)&sR[sw(r0, cc)], qvf0, p0);
            p1 = MFMA16(*(const f16x8*)&sR[sw(r1, cc)], qvf0, p1);
            p2 = MFMA16(*(const f16x8*)&sR[sw(r2, cc)], qvf0, p2);
            p3 = MFMA16(*(const f16x8*)&sR[sw(r3, cc)], qvf0, p3);
            p4 = MFMA16(*(const f16x8*)&sR[sw(r4, cc)], qvf0, p4);
            cc = 32 + 8*G;
            p0 = MFMA16(*(const f16x8*)&sR[sw(r0, cc)], qvf1, p0);
            p1 = MFMA16(*(const f16x8*)&sR[sw(r1, cc)], qvf1, p1);
            p2 = MFMA16(*(const f16x8*)&sR[sw(r2, cc)], qvf1, p2);
            p3 = MFMA16(*(const f16x8*)&sR[sw(r3, cc)], qvf1, p3);
            p4 = MFMA16(*(const f16x8*)&sR[sw(r4, cc)], qvf1, p4);
        }
        // ---- scatter band (transposed): sPT[wv][query q][bandrow] ----
        {
            _Float16* dst = &sPT[wv*WSTR + q*PST + 4*G];
            *(f16x4*)&dst[ 0] = (f16x4){(_Float16)p0[0],(_Float16)p0[1],(_Float16)p0[2],(_Float16)p0[3]};
            *(f16x4*)&dst[16] = (f16x4){(_Float16)p1[0],(_Float16)p1[1],(_Float16)p1[2],(_Float16)p1[3]};
            *(f16x4*)&dst[32] = (f16x4){(_Float16)p2[0],(_Float16)p2[1],(_Float16)p2[2],(_Float16)p2[3]};
            *(f16x4*)&dst[48] = (f16x4){(_Float16)p3[0],(_Float16)p3[1],(_Float16)p3[2],(_Float16)p3[3]};
            *(f16x4*)&dst[64] = (f16x4){(_Float16)p4[0],(_Float16)p4[1],(_Float16)p4[2],(_Float16)p4[3]};
        }
        // ---- fallback column (query i0+128), wave 7 only: VALU dots ----
        if (wv == 7) {
            int sl = sbase + lane; if (sl >= RING) sl -= RING;
            float acc = 0.f;
#pragma unroll
            for (int c8 = 0; c8 < 8; ++c8) {
                f16x8 rv = *(const f16x8*)&sR[sw(sl, 8*c8)];
                f16x8 qx = *(const f16x8*)&sQx[8*c8];
#pragma unroll
                for (int e = 0; e < 8; ++e) acc = fmaf((float)rv[e], (float)qx[e], acc);
            }
            sPT[FB + 16 + lane] = (_Float16)acc;
        }
        // ---- PV of tile t-1 ----
        if (t > 0) {
            float cg0 = __shfl(corr, 4*G + 0);
            float cg1 = __shfl(corr, 4*G + 1);
            float cg2 = __shfl(corr, 4*G + 2);
            float cg3 = __shfl(corr, 4*G + 3);
            f32x4 cg = {cg0, cg1, cg2, cg3};
            o0 *= cg; o1 *= cg; o2 *= cg; o3 *= cg;
            const _Float16* vt = sVt[(t-1) & 1];
            int cc = 8*G;
            o0 = MFMA16(wf0, *(const f16x8*)&vt[sw( 0+q, cc)], o0);
            o1 = MFMA16(wf0, *(const f16x8*)&vt[sw(16+q, cc)], o1);
            o2 = MFMA16(wf0, *(const f16x8*)&vt[sw(32+q, cc)], o2);
            o3 = MFMA16(wf0, *(const f16x8*)&vt[sw(48+q, cc)], o3);
            cc = 32 + 8*G;
            o0 = MFMA16(wf1, *(const f16x8*)&vt[sw( 0+q, cc)], o0);
            o1 = MFMA16(wf1, *(const f16x8*)&vt[sw(16+q, cc)], o1);
            o2 = MFMA16(wf1, *(const f16x8*)&vt[sw(32+q, cc)], o2);
            o3 = MFMA16(wf1, *(const f16x8*)&vt[sw(48+q, cc)], o3);
        }
        __builtin_amdgcn_s_setprio(0);
        __syncthreads();
        // ================= gather + softmax + wfrag + stage =================
        {
            const int ii = i0 + 16*wv + q - j0;            // i - j0
            const int b1 = wv*WSTR + q*PST + 15 + 4*G - q; // case1 base (col q)
            const int b2 = b1 + PST + ((q == 15) ? 16 : 0);// case2 base (col q+1 / next strip / fallback)
            float sc[16];
#pragma unroll
            for (int t4 = 0; t4 < 4; ++t4) {
#pragma unroll
                for (int r = 0; r < 4; ++r) {
                    const int off = r + 16*t4;
                    const int jrel = 4*G + off;
                    const float v1 = (float)sPT[b1 + off];
                    const float v2 = (float)sPT[b2 + off];
                    const int dj = jrel - ii;
                    const float add = (dj <= 0) ? v1 : ((dj == 1) ? 0.f : v2);
                    const float cv = (t4 == 0) ? c0[r] : (t4 == 1) ? c1[r] : (t4 == 2) ? c2[r] : c3[r];
                    sc[4*t4 + r] = cv + add;
                }
            }
            float mA = fmaxf(fmaxf(fmaxf(sc[0],sc[1]),fmaxf(sc[2],sc[3])),
                             fmaxf(fmaxf(sc[4],sc[5]),fmaxf(sc[6],sc[7])));
            float mB = fmaxf(fmaxf(fmaxf(sc[8],sc[9]),fmaxf(sc[10],sc[11])),
                             fmaxf(fmaxf(sc[12],sc[13]),fmaxf(sc[14],sc[15])));
            float mx = fmaxf(mA, mB);
            mx = fmaxf(mx, __shfl_xor(mx, 16));
            mx = fmaxf(mx, __shfl_xor(mx, 32));
            const float mnew = fmaxf(m_run, mx);
            corr = exp2f(m_run - mnew);
            m_run = mnew;
#pragma unroll
            for (int i = 0; i < 16; ++i) sc[i] = exp2f(sc[i] - mnew);
            float sA2 = ((sc[0]+sc[1])+(sc[2]+sc[3])) + ((sc[4]+sc[5])+(sc[6]+sc[7]));
            float sB2 = ((sc[8]+sc[9])+(sc[10]+sc[11])) + ((sc[12]+sc[13])+(sc[14]+sc[15]));
            float ssum = sA2 + sB2;
            ssum += __shfl_xor(ssum, 16);
            ssum += __shfl_xor(ssum, 32);
            l_run = l_run * corr + ssum;
            // pack exp'd weights: pkd[2*t4+w]
            unsigned pkd[8];
#pragma unroll
            for (int t4 = 0; t4 < 4; ++t4) {
                pkd[2*t4+0] = pk2(sc[4*t4+0], sc[4*t4+1]);
                pkd[2*t4+1] = pk2(sc[4*t4+2], sc[4*t4+3]);
            }
            const int s0 = q + 32*(G & 1);
            const int s1 = s0 + 16;
            const bool lo = (G < 2);
            {   // kl = 0 : keys 0..31
                unsigned A0 = (unsigned)__shfl((int)pkd[0], s0);
                unsigned A1 = (unsigned)__shfl((int)pkd[1], s0);
                unsigned A2 = (unsigned)__shfl((int)pkd[0], s1);
                unsigned A3 = (unsigned)__shfl((int)pkd[1], s1);
                unsigned B0 = (unsigned)__shfl((int)pkd[2], s0);
                unsigned B1 = (unsigned)__shfl((int)pkd[3], s0);
                unsigned B2 = (unsigned)__shfl((int)pkd[2], s1);
                unsigned B3 = (unsigned)__shfl((int)pkd[3], s1);
                wf0 = mk8(lo?A0:B0, lo?A1:B1, lo?A2:B2, lo?A3:B3);
            }
            {   // kl = 1 : keys 32..63
                unsigned A0 = (unsigned)__shfl((int)pkd[4], s0);
                unsigned A1 = (unsigned)__shfl((int)pkd[5], s0);
                unsigned A2 = (unsigned)__shfl((int)pkd[4], s1);
                unsigned A3 = (unsigned)__shfl((int)pkd[5], s1);
                unsigned B0 = (unsigned)__shfl((int)pkd[6], s0);
                unsigned B1 = (unsigned)__shfl((int)pkd[7], s0);
                unsigned B2 = (unsigned)__shfl((int)pkd[6], s1);
                unsigned B3 = (unsigned)__shfl((int)pkd[7], s1);
                wf1 = mk8(lo?A0:B0, lo?A1:B1, lo?A2:B2, lo?A3:B3);
            }
            // ---- stage tile t+1 DIRECTLY (load -> convert -> ds_write) ----
            // No registers live across barriers; co-resident block hides latency.
            if (t + 1 < NT) {
                const float* s = Kb + (size_t)(j0 + 64 + rK)*HD + cK;
                float4 ka = ld4(s), kb = ld4(s+4);
                const float* sA = Vb + (size_t)(j0 + 64 + kp2)*HD + d0v;
                float4 va = ld4(sA), vb2 = ld4(sA + HD);
                int d = j0 - i0 + 65 + rK;
                int row = (d <= 0) ? (1023 + d) : ((d >= 2) ? d - 2 : 0);
                const float* sr = Rh + (size_t)row*HD + cK;
                float4 ra = ld4(sr), rb = ld4(sr+4);
                *(f16x8*)&sK[sw(rK, cK)] = cvt8(ka, kb);
                _Float16* vt = sVt[(t+1) & 1];
                *(f16x2*)&vt[sw(d0v+0, kp2)] = (f16x2){(_Float16)va.x,(_Float16)vb2.x};
                *(f16x2*)&vt[sw(d0v+1, kp2)] = (f16x2){(_Float16)va.y,(_Float16)vb2.y};
                *(f16x2*)&vt[sw(d0v+2, kp2)] = (f16x2){(_Float16)va.z,(_Float16)vb2.z};
                *(f16x2*)&vt[sw(d0v+3, kp2)] = (f16x2){(_Float16)va.w,(_Float16)vb2.w};
                int slot = (d + 1536) % RING;
                *(f16x8*)&sR[sw(slot, cK)] = cvt8(ra, rb);
            }
            sbase += 64; if (sbase >= RING) sbase -= RING;
        }
        __syncthreads();
    }
    // ================= epilogue: PV of tile 15 + output =================
    {
        float cg0 = __shfl(corr, 4*G + 0);
        float cg1 = __shfl(corr, 4*G + 1);
        float cg2 = __shfl(corr, 4*G + 2);
        float cg3 = __shfl(corr, 4*G + 3);
        f32x4 cg = {cg0, cg1, cg2, cg3};
        o0 *= cg; o1 *= cg; o2 *= cg; o3 *= cg;
        const _Float16* vt = sVt[(NT-1) & 1];
        int cc = 8*G;
        o0 = MFMA16(wf0, *(const f16x8*)&vt[sw( 0+q, cc)], o0);
        o1 = MFMA16(wf0, *(const f16x8*)&vt[sw(16+q, cc)], o1);
        o2 = MFMA16(wf0, *(const f16x8*)&vt[sw(32+q, cc)], o2);
        o3 = MFMA16(wf0, *(const f16x8*)&vt[sw(48+q, cc)], o3);
        cc = 32 + 8*G;
        o0 = MFMA16(wf1, *(const f16x8*)&vt[sw( 0+q, cc)], o0);
        o1 = MFMA16(wf1, *(const f16x8*)&vt[sw(16+q, cc)], o1);
        o2 = MFMA16(wf1, *(const f16x8*)&vt[sw(32+q, cc)], o2);
        o3 = MFMA16(wf1, *(const f16x8*)&vt[sw(48+q, cc)], o3);
    }
    {
        float i0v = 1.f / __shfl(l_run, 4*G + 0);
        float i1v = 1.f / __shfl(l_run, 4*G + 1);
        float i2v = 1.f / __shfl(l_run, 4*G + 2);
        float i3v = 1.f / __shfl(l_run, 4*G + 3);
        f32x4 inv = {i0v, i1v, i2v, i3v};
#pragma unroll
        for (int reg = 0; reg < 4; ++reg) {
            size_t base = ((size_t)bh*SEQ + i0 + 16*wv + 4*G + reg) * HD + q;
            O[base +  0] = o0[reg] * inv[reg];
            O[base + 16] = o1[reg] * inv[reg];
            O[base + 32] = o2[reg] * inv[reg];
            O[base + 48] = o3[reg] * inv[reg];
        }
    }
}

extern "C" void kernel_launch(void* const* d_in, const int* in_sizes, int n_in,
                              void* d_out, int out_size, void* d_ws, size_t ws_size,
                              hipStream_t stream) {
    const float* Q  = (const float*)d_in[0];
    const float* K  = (const float*)d_in[1];
    const float* V  = (const float*)d_in[2];
    const float* UB = (const float*)d_in[3];
    const float* VB = (const float*)d_in[4];
    const float* R  = (const float*)d_in[5];
    float* O = (float*)d_out;

    rpsdpa7<<<dim3(512), dim3(512), 0, stream>>>(Q, K, V, UB, VB, R, O);
}

// Round 9
// 82.916 us; speedup vs baseline: 1.7473x; 1.0260x over previous
//
#include <hip/hip_runtime.h>

#define SEQ  1024
#define HD   64
#define QTB  128
#define NT   16
#define RING 192
#define PST  84
#define WSTR (16*PST)    // per-wave strip stride (16 query cols)
#define FB   (8*WSTR)    // fallback column base
#define L2E  1.44269504f

typedef __attribute__((ext_vector_type(8))) _Float16 f16x8;
typedef __attribute__((ext_vector_type(4))) _Float16 f16x4;
typedef __attribute__((ext_vector_type(2))) _Float16 f16x2;
typedef __attribute__((ext_vector_type(4))) float    f32x4;

#define MFMA16(a,b,c)  __builtin_amdgcn_mfma_f32_16x16x32_f16(a,b,c,0,0,0)
#define MFMA161(a,b,c) __builtin_amdgcn_mfma_f32_16x16x16f16(a,b,c,0,0,0)

// swizzled element index into a [rows][64] f16 tile (128B rows)
__device__ __forceinline__ int sw(int row, int c) {
    return (row << 6) + (c ^ ((row & 7) << 3));
}
__device__ __forceinline__ float4 ld4(const float* p) { return *(const float4*)p; }
__device__ __forceinline__ f16x8 cvt8(float4 a, float4 b) {
    return (f16x8){(_Float16)a.x,(_Float16)a.y,(_Float16)a.z,(_Float16)a.w,
                   (_Float16)b.x,(_Float16)b.y,(_Float16)b.z,(_Float16)b.w};
}
// (q*K^-0.5 + bias) * log2(e)  -> scores arrive in log2 domain
__device__ __forceinline__ f16x8 biasf8(float4 qa, float4 qb, float4 ba, float4 bb) {
    return (f16x8){(_Float16)(fmaf(qa.x,0.125f,ba.x)*L2E),(_Float16)(fmaf(qa.y,0.125f,ba.y)*L2E),
                   (_Float16)(fmaf(qa.z,0.125f,ba.z)*L2E),(_Float16)(fmaf(qa.w,0.125f,ba.w)*L2E),
                   (_Float16)(fmaf(qb.x,0.125f,bb.x)*L2E),(_Float16)(fmaf(qb.y,0.125f,bb.y)*L2E),
                   (_Float16)(fmaf(qb.z,0.125f,bb.z)*L2E),(_Float16)(fmaf(qb.w,0.125f,bb.w)*L2E)};
}

__global__ __launch_bounds__(512, 4)
void rpsdpa8(const float* __restrict__ Q, const float* __restrict__ Km,
             const float* __restrict__ Vm, const float* __restrict__ UB,
             const float* __restrict__ VB, const float* __restrict__ Rm,
             float* __restrict__ O)
{
    __shared__ __attribute__((aligned(16))) _Float16 sK[64*64];
    __shared__ __attribute__((aligned(16))) _Float16 sVt[2][64*64];
    __shared__ __attribute__((aligned(16))) _Float16 sR[RING*64];
    __shared__ __attribute__((aligned(16))) _Float16 sPT[FB + PST];
    __shared__ __attribute__((aligned(16))) _Float16 sQx[64];

    const int tid  = threadIdx.x;
    const int wv   = tid >> 6;
    const int lane = tid & 63;
    const int q    = lane & 15;
    const int G    = lane >> 4;

    // head-major XCD swizzle: XCD (= bid%8) carries heads {x, x+8} only,
    // so the per-head R table is L2-resident per XCD.
    const int bid = blockIdx.x;
    const int x   = bid & 7;
    const int y   = bid >> 3;
    const int h   = x + ((y & 1) << 3);
    const int n   = (y >> 1) & 3;
    const int bh  = n * 16 + h;
    const int i0  = (y >> 3) * QTB;

    const float* Qb = Q  + (size_t)bh * SEQ * HD;
    const float* Kb = Km + (size_t)bh * SEQ * HD;
    const float* Vb = Vm + (size_t)bh * SEQ * HD;
    const float* Rh = Rm + (size_t)h * 2048 * HD;

    // ---- qu/qv B-fragments: this lane's query row = i0 + 16*wv + q ----
    f16x8 qu0, qu1, qvf0, qvf1;
    {
        const float* qr = Qb + (size_t)(i0 + 16*wv + q) * HD;
        const float* ub = UB + h * HD;
        const float* vb = VB + h * HD;
        {   int c = 8*G;
            float4 qa = ld4(qr+c), qb2 = ld4(qr+c+4);
            qu0  = biasf8(qa,qb2, ld4(ub+c), ld4(ub+c+4));
            qvf0 = biasf8(qa,qb2, ld4(vb+c), ld4(vb+c+4)); }
        {   int c = 32 + 8*G;
            float4 qa = ld4(qr+c), qb2 = ld4(qr+c+4);
            qu1  = biasf8(qa,qb2, ld4(ub+c), ld4(ub+c+4));
            qvf1 = biasf8(qa,qb2, ld4(vb+c), ld4(vb+c+4)); }
    }
    // ---- sQx: q_v row i0+128 (fallback column source), log2-scaled ----
    if (tid < 16) {
        int c0 = tid * 4;
        float4 v = make_float4(0.f,0.f,0.f,0.f);
        if (i0 + 128 < SEQ) {
            float4 q4 = ld4(Qb + (size_t)(i0+128)*HD + c0);
            float4 b4 = ld4(VB + h*HD + c0);
            v = make_float4(fmaf(q4.x,0.125f,b4.x)*L2E, fmaf(q4.y,0.125f,b4.y)*L2E,
                            fmaf(q4.z,0.125f,b4.z)*L2E, fmaf(q4.w,0.125f,b4.w)*L2E);
        }
        *(f16x4*)&sQx[c0] = (f16x4){(_Float16)v.x,(_Float16)v.y,(_Float16)v.z,(_Float16)v.w};
    }
    // ---- prologue staging ----
    const int rK  = tid >> 3;            // 0..63
    const int cK  = (tid & 7) * 8;       // 0..56
    const int kp2 = (tid & 31) * 2;      // 0..62 (V key pair)
    const int d0v = (tid >> 5) * 4;      // 0..60 (V dim chunk)
    {
        const float* s = Kb + (size_t)rK*HD + cK;
        *(f16x8*)&sK[sw(rK, cK)] = cvt8(ld4(s), ld4(s+4));
    }
    {
        const float* sA = Vb + (size_t)kp2*HD + d0v;
        float4 a = ld4(sA), b2 = ld4(sA + HD);
        _Float16* vt = sVt[0];
        *(f16x2*)&vt[sw(d0v+0, kp2)] = (f16x2){(_Float16)a.x,(_Float16)b2.x};
        *(f16x2*)&vt[sw(d0v+1, kp2)] = (f16x2){(_Float16)a.y,(_Float16)b2.y};
        *(f16x2*)&vt[sw(d0v+2, kp2)] = (f16x2){(_Float16)a.z,(_Float16)b2.z};
        *(f16x2*)&vt[sw(d0v+3, kp2)] = (f16x2){(_Float16)a.w,(_Float16)b2.w};
    }
#pragma unroll 1
    for (int p = 0; p < 3; ++p) {
        int d = -i0 - 127 + p*64 + rK;
        int row = (d <= 0) ? (1023 + d) : ((d >= 2) ? d - 2 : 0);
        int slot = (d + 1536) % RING;
        const float* s = Rh + (size_t)row*HD + cK;
        *(f16x8*)&sR[sw(slot, cK)] = cvt8(ld4(s), ld4(s+4));
    }
    __syncthreads();

    int sbase = ((-i0 - 16*wv - 15) + 1536) % RING;
    float m_run = -3.0e38f, l_run = 0.f, corr = 0.f;
    f32x4 o0 = {}, o1 = {}, o2 = {}, o3 = {};
    f16x4 wfa0 = {}, wfa1 = {}, wfa2 = {}, wfa3 = {};

#pragma unroll 1
    for (int t = 0; t < NT; ++t) {
        const int j0 = t * 64;
        __builtin_amdgcn_s_setprio(1);
        // ---- content: C[key][query], A = K rows, B = qu ----
        f32x4 c0 = {}, c1 = {}, c2 = {}, c3 = {};
        {
            int cc = 8*G;
            c0 = MFMA16(*(const f16x8*)&sK[sw( 0+q, cc)], qu0, c0);
            c1 = MFMA16(*(const f16x8*)&sK[sw(16+q, cc)], qu0, c1);
            c2 = MFMA16(*(const f16x8*)&sK[sw(32+q, cc)], qu0, c2);
            c3 = MFMA16(*(const f16x8*)&sK[sw(48+q, cc)], qu0, c3);
            cc = 32 + 8*G;
            c0 = MFMA16(*(const f16x8*)&sK[sw( 0+q, cc)], qu1, c0);
            c1 = MFMA16(*(const f16x8*)&sK[sw(16+q, cc)], qu1, c1);
            c2 = MFMA16(*(const f16x8*)&sK[sw(32+q, cc)], qu1, c2);
            c3 = MFMA16(*(const f16x8*)&sK[sw(48+q, cc)], qu1, c3);
        }
        // ---- pos band: C[bandpos][query], A = R band rows, B = qv ----
        f32x4 p0 = {}, p1 = {}, p2 = {}, p3 = {}, p4 = {};
        {
            int r0 = sbase + q;       if (r0 >= RING) r0 -= RING;
            int r1 = sbase + 16 + q;  if (r1 >= RING) r1 -= RING;
            int r2 = sbase + 32 + q;  if (r2 >= RING) r2 -= RING;
            int r3 = sbase + 48 + q;  if (r3 >= RING) r3 -= RING;
            int r4 = sbase + 64 + q;  if (r4 >= RING) r4 -= RING;
            int cc = 8*G;
            p0 = MFMA16(*(const f16x8*)&sR[sw(r0, cc)], qvf0, p0);
            p1 = MFMA16(*(const f16x8*)&sR[sw(r1, cc)], qvf0, p1);
            p2 = MFMA16(*(const f16x8*)&sR[sw(r2, cc)], qvf0, p2);
            p3 = MFMA16(*(const f16x8*)&sR[sw(r3, cc)], qvf0, p3);
            p4 = MFMA16(*(const f16x8*)&sR[sw(r4, cc)], qvf0, p4);
            cc = 32 + 8*G;
            p0 = MFMA16(*(const f16x8*)&sR[sw(r0, cc)], qvf1, p0);
            p1 = MFMA16(*(const f16x8*)&sR[sw(r1, cc)], qvf1, p1);
            p2 = MFMA16(*(const f16x8*)&sR[sw(r2, cc)], qvf1, p2);
            p3 = MFMA16(*(const f16x8*)&sR[sw(r3, cc)], qvf1, p3);
            p4 = MFMA16(*(const f16x8*)&sR[sw(r4, cc)], qvf1, p4);
        }
        // ---- scatter band (transposed): sPT[wv][query q][bandrow] ----
        {
            _Float16* dst = &sPT[wv*WSTR + q*PST + 4*G];
            *(f16x4*)&dst[ 0] = (f16x4){(_Float16)p0[0],(_Float16)p0[1],(_Float16)p0[2],(_Float16)p0[3]};
            *(f16x4*)&dst[16] = (f16x4){(_Float16)p1[0],(_Float16)p1[1],(_Float16)p1[2],(_Float16)p1[3]};
            *(f16x4*)&dst[32] = (f16x4){(_Float16)p2[0],(_Float16)p2[1],(_Float16)p2[2],(_Float16)p2[3]};
            *(f16x4*)&dst[48] = (f16x4){(_Float16)p3[0],(_Float16)p3[1],(_Float16)p3[2],(_Float16)p3[3]};
            *(f16x4*)&dst[64] = (f16x4){(_Float16)p4[0],(_Float16)p4[1],(_Float16)p4[2],(_Float16)p4[3]};
        }
        // ---- fallback column (query i0+128), wave 7 only: VALU dots ----
        if (wv == 7) {
            int sl = sbase + lane; if (sl >= RING) sl -= RING;
            float acc = 0.f;
#pragma unroll
            for (int c8 = 0; c8 < 8; ++c8) {
                f16x8 rv = *(const f16x8*)&sR[sw(sl, 8*c8)];
                f16x8 qx = *(const f16x8*)&sQx[8*c8];
#pragma unroll
                for (int e = 0; e < 8; ++e) acc = fmaf((float)rv[e], (float)qx[e], acc);
            }
            sPT[FB + 16 + lane] = (_Float16)acc;
        }
        // ---- PV of tile t-1: 16x16x16 MFMAs, A-frags in-lane (no shuffles) ----
        if (t > 0) {
            float cg0 = __shfl(corr, 4*G + 0);
            float cg1 = __shfl(corr, 4*G + 1);
            float cg2 = __shfl(corr, 4*G + 2);
            float cg3 = __shfl(corr, 4*G + 3);
            f32x4 cg = {cg0, cg1, cg2, cg3};
            o0 *= cg; o1 *= cg; o2 *= cg; o3 *= cg;
            const _Float16* vt = sVt[(t-1) & 1];
#define PV_STEP(KB, A) { \
            o0 = MFMA161(A, *(const f16x4*)&vt[sw( 0+q, 16*KB+4*G)], o0); \
            o1 = MFMA161(A, *(const f16x4*)&vt[sw(16+q, 16*KB+4*G)], o1); \
            o2 = MFMA161(A, *(const f16x4*)&vt[sw(32+q, 16*KB+4*G)], o2); \
            o3 = MFMA161(A, *(const f16x4*)&vt[sw(48+q, 16*KB+4*G)], o3); }
            PV_STEP(0, wfa0) PV_STEP(1, wfa1) PV_STEP(2, wfa2) PV_STEP(3, wfa3)
        }
        __builtin_amdgcn_s_setprio(0);
        __syncthreads();
        // ================= gather + softmax + wfrag + stage =================
        {
            const int ii = i0 + 16*wv + q - j0;            // i - j0
            const int b1 = wv*WSTR + q*PST + 15 + 4*G - q; // case1 base (col q)
            const int b2 = b1 + PST + ((q == 15) ? 16 : 0);// case2 base (col q+1 / next strip / fallback)
            float sc[16];
#pragma unroll
            for (int t4 = 0; t4 < 4; ++t4) {
#pragma unroll
                for (int r = 0; r < 4; ++r) {
                    const int off = r + 16*t4;
                    const int jrel = 4*G + off;
                    const float v1 = (float)sPT[b1 + off];
                    const float v2 = (float)sPT[b2 + off];
                    const int dj = jrel - ii;
                    const float add = (dj <= 0) ? v1 : ((dj == 1) ? 0.f : v2);
                    const float cv = (t4 == 0) ? c0[r] : (t4 == 1) ? c1[r] : (t4 == 2) ? c2[r] : c3[r];
                    sc[4*t4 + r] = cv + add;
                }
            }
            float mA = fmaxf(fmaxf(fmaxf(sc[0],sc[1]),fmaxf(sc[2],sc[3])),
                             fmaxf(fmaxf(sc[4],sc[5]),fmaxf(sc[6],sc[7])));
            float mB = fmaxf(fmaxf(fmaxf(sc[8],sc[9]),fmaxf(sc[10],sc[11])),
                             fmaxf(fmaxf(sc[12],sc[13]),fmaxf(sc[14],sc[15])));
            float mx = fmaxf(mA, mB);
            mx = fmaxf(mx, __shfl_xor(mx, 16));
            mx = fmaxf(mx, __shfl_xor(mx, 32));
            const float mnew = fmaxf(m_run, mx);
            corr = exp2f(m_run - mnew);
            m_run = mnew;
#pragma unroll
            for (int i = 0; i < 16; ++i) sc[i] = exp2f(sc[i] - mnew);
            float sA2 = ((sc[0]+sc[1])+(sc[2]+sc[3])) + ((sc[4]+sc[5])+(sc[6]+sc[7]));
            float sB2 = ((sc[8]+sc[9])+(sc[10]+sc[11])) + ((sc[12]+sc[13])+(sc[14]+sc[15]));
            float ssum = sA2 + sB2;
            ssum += __shfl_xor(ssum, 16);
            ssum += __shfl_xor(ssum, 32);
            l_run = l_run * corr + ssum;
            // PV A-fragments: keys 4G+{0..3} of block t4 are ALREADY in-lane
            wfa0 = (f16x4){(_Float16)sc[0], (_Float16)sc[1], (_Float16)sc[2], (_Float16)sc[3]};
            wfa1 = (f16x4){(_Float16)sc[4], (_Float16)sc[5], (_Float16)sc[6], (_Float16)sc[7]};
            wfa2 = (f16x4){(_Float16)sc[8], (_Float16)sc[9], (_Float16)sc[10],(_Float16)sc[11]};
            wfa3 = (f16x4){(_Float16)sc[12],(_Float16)sc[13],(_Float16)sc[14],(_Float16)sc[15]};
            // ---- stage tile t+1 DIRECTLY (load -> convert -> ds_write) ----
            if (t + 1 < NT) {
                const float* s = Kb + (size_t)(j0 + 64 + rK)*HD + cK;
                float4 ka = ld4(s), kb = ld4(s+4);
                const float* sA = Vb + (size_t)(j0 + 64 + kp2)*HD + d0v;
                float4 va = ld4(sA), vb2 = ld4(sA + HD);
                int d = j0 - i0 + 65 + rK;
                int row = (d <= 0) ? (1023 + d) : ((d >= 2) ? d - 2 : 0);
                const float* sr = Rh + (size_t)row*HD + cK;
                float4 ra = ld4(sr), rb = ld4(sr+4);
                *(f16x8*)&sK[sw(rK, cK)] = cvt8(ka, kb);
                _Float16* vt = sVt[(t+1) & 1];
                *(f16x2*)&vt[sw(d0v+0, kp2)] = (f16x2){(_Float16)va.x,(_Float16)vb2.x};
                *(f16x2*)&vt[sw(d0v+1, kp2)] = (f16x2){(_Float16)va.y,(_Float16)vb2.y};
                *(f16x2*)&vt[sw(d0v+2, kp2)] = (f16x2){(_Float16)va.z,(_Float16)vb2.z};
                *(f16x2*)&vt[sw(d0v+3, kp2)] = (f16x2){(_Float16)va.w,(_Float16)vb2.w};
                int slot = (d + 1536) % RING;
                *(f16x8*)&sR[sw(slot, cK)] = cvt8(ra, rb);
            }
            sbase += 64; if (sbase >= RING) sbase -= RING;
        }
        __syncthreads();
    }
    // ================= epilogue: PV of tile 15 + output =================
    {
        float cg0 = __shfl(corr, 4*G + 0);
        float cg1 = __shfl(corr, 4*G + 1);
        float cg2 = __shfl(corr, 4*G + 2);
        float cg3 = __shfl(corr, 4*G + 3);
        f32x4 cg = {cg0, cg1, cg2, cg3};
        o0 *= cg; o1 *= cg; o2 *= cg; o3 *= cg;
        const _Float16* vt = sVt[(NT-1) & 1];
        PV_STEP(0, wfa0) PV_STEP(1, wfa1) PV_STEP(2, wfa2) PV_STEP(3, wfa3)
#undef PV_STEP
    }
    {
        float i0v = 1.f / __shfl(l_run, 4*G + 0);
        float i1v = 1.f / __shfl(l_run, 4*G + 1);
        float i2v = 1.f / __shfl(l_run, 4*G + 2);
        float i3v = 1.f / __shfl(l_run, 4*G + 3);
        f32x4 inv = {i0v, i1v, i2v, i3v};
#pragma unroll
        for (int reg = 0; reg < 4; ++reg) {
            size_t base = ((size_t)bh*SEQ + i0 + 16*wv + 4*G + reg) * HD + q;
            O[base +  0] = o0[reg] * inv[reg];
            O[base + 16] = o1[reg] * inv[reg];
            O[base + 32] = o2[reg] * inv[reg];
            O[base + 48] = o3[reg] * inv[reg];
        }
    }
}

extern "C" void kernel_launch(void* const* d_in, const int* in_sizes, int n_in,
                              void* d_out, int out_size, void* d_ws, size_t ws_size,
                              hipStream_t stream) {
    const float* Q  = (const float*)d_in[0];
    const float* K  = (const float*)d_in[1];
    const float* V  = (const float*)d_in[2];
    const float* UB = (const float*)d_in[3];
    const float* VB = (const float*)d_in[4];
    const float* R  = (const float*)d_in[5];
    float* O = (float*)d_out;

    rpsdpa8<<<dim3(512), dim3(512), 0, stream>>>(Q, K, V, UB, VB, R, O);
}